// Round 2
// baseline (1922.333 us; speedup 1.0000x reference)
//
#include <hip/hip_runtime.h>
#include <math.h>

#define TLEN 1024
#define DDIM 256
#define NH_  4
#define NDIM 2048
#define HN   8192
#define NCH  16
#define CHK  64
#define VP_  50304
#define SCALE_Q 0.022097086912079608f  // 2048^-0.5

typedef unsigned short u16;
typedef __attribute__((ext_vector_type(8))) short short8;
typedef __attribute__((ext_vector_type(4))) float f32x4;

#define MFMA16(a,b,c) __builtin_amdgcn_mfma_f32_16x16x32_bf16((a),(b),(c),0,0,0)

__device__ __forceinline__ float bf2f(u16 u){ return __uint_as_float(((unsigned)u)<<16); }
__device__ __forceinline__ u16 f2bf(float f){
  unsigned x = __float_as_uint(f);
  return (u16)((x + 0x7fffu + ((x>>16)&1u)) >> 16);
}
__device__ __forceinline__ float wave_sum(float v){
  #pragma unroll
  for(int o=1;o<64;o<<=1) v += __shfl_xor(v,o,64);
  return v;
}
__device__ __forceinline__ float block_sum(float v, float* tmp){
  v = wave_sum(v);
  __syncthreads();
  if((threadIdx.x&63)==0) tmp[threadIdx.x>>6]=v;
  __syncthreads();
  return tmp[0]+tmp[1]+tmp[2]+tmp[3];
}

// ---- LDS tile helpers: 64-col bf16 tiles, rows 128B, XOR-swizzled 16B slots ----
__device__ __forceinline__ void ld_tile(u16* dst, const u16* src, int ldg, int tid){
  #pragma unroll
  for(int p=0;p<2;p++){
    int r = p*32 + (tid>>3), cb = tid&7;
    short8 v = *(const short8*)(src + (size_t)r*ldg + cb*8);
    *(short8*)((char*)dst + r*128 + ((cb*16) ^ ((r&7)<<4))) = v;
  }
}
// dst[n][t] = src[t][n]  (64x64)
__device__ __forceinline__ void ld_tileT(u16* dst, const u16* src, int ldg, int tid){
  #pragma unroll
  for(int p=0;p<2;p++){
    int idx = p*256 + tid; int t = idx>>3, cb = idx&7;
    short8 v = *(const short8*)(src + (size_t)t*ldg + cb*8);
    #pragma unroll
    for(int j=0;j<8;j++){
      int n = cb*8+j;
      *(u16*)((char*)dst + n*128 + ((t*2) ^ ((n&7)<<4))) = (u16)v[j];
    }
  }
}
// dst[d][t] (256x64) = src[t][d] (64x256)
__device__ __forceinline__ void ld_vbT(u16* dst, const u16* src, int tid){
  #pragma unroll
  for(int p=0;p<8;p++){
    int idx = p*256 + tid; int t = idx>>5, cb = idx&31;
    short8 v = *(const short8*)(src + (size_t)t*DDIM + cb*8);
    #pragma unroll
    for(int j=0;j<8;j++){
      int d = cb*8+j;
      *(u16*)((char*)dst + d*128 + ((t*2) ^ ((d&7)<<4))) = (u16)v[j];
    }
  }
}
__device__ __forceinline__ short8 frag64(const u16* lds, int row, int k){
  return *(const short8*)((const char*)lds + row*128 + ((k*2) ^ ((row&7)<<4)));
}

// ---- setup kernels ----
__global__ void k_tables(float* cosT, float* sinT){
  int t = blockIdx.x, i = threadIdx.x; // 128 threads
  float inv_freq = exp2f(-18.0f * (float)(2*i) * (1.0f/256.0f));
  float fr = (float)t * inv_freq;
  float xsc = ((float)(2*i) + 102.4f) * (1.0f/358.4f);
  float power = ((float)t - 512.0f) * (1.0f/512.0f);
  float sc = exp2f(power * log2f(xsc));
  cosT[t*128+i] = cosf(fr)*sc;
  sinT[t*128+i] = sinf(fr)*sc;
}
__global__ void k_cvt(const float* in, u16* out, int n){
  for(int i = blockIdx.x*blockDim.x + threadIdx.x; i < n; i += gridDim.x*blockDim.x)
    out[i] = f2bf(in[i]);
}
__global__ __launch_bounds__(256) void k_embed(const float* emb, const int* idx, float* x, float* x0){
  __shared__ float tmp[4];
  int t = blockIdx.x, d = threadIdx.x;
  float v = emb[(size_t)idx[t]*DDIM + d];
  float s = block_sum(v*v, tmp);
  float o = v * rsqrtf(s*(1.0f/DDIM) + 1e-5f);
  x[t*DDIM+d]=o; x0[t*DDIM+d]=o;
}
__global__ void k_xin(const float* x, const float* x0, const float* rl, const float* xl, int li,
                      float* xin, u16* xin_bf, float* yraw){
  int i = blockIdx.x*256 + threadIdx.x;
  float v = rl[li]*x[i] + xl[li]*x0[i];
  xin[i]=v; xin_bf[i]=f2bf(v); yraw[i]=0.f;
}

// ---- generic bf16 GEMM: C = epi(A(MxK) @ B(NxK)^T) ----
// EPI: 0=fp32 store(/atomic), 1=sqrelu->bf16, 2=sqrelu/1024->bf16, 3=aux*sqrelu->bf16
template<int EPI, bool ATOMIC>
__global__ __launch_bounds__(256) void k_gemm(
  const u16* __restrict__ A, int lda, const u16* __restrict__ B, int ldb,
  void* Cv, int ldc, const u16* __restrict__ aux, int ldaux, int kchunk)
{
  __shared__ __align__(16) u16 sA[128*64];
  __shared__ __align__(16) u16 sB[128*64];
  const int m0 = blockIdx.x*128, n0 = blockIdx.y*128;
  const int k0 = blockIdx.z*kchunk;
  const int tid = threadIdx.x, lane = tid&63, wv = tid>>6;
  const int wr = (wv>>1)*64, wc = (wv&1)*64;
  f32x4 acc[4][4];
  #pragma unroll
  for(int i=0;i<4;i++)
    #pragma unroll
    for(int j=0;j<4;j++) acc[i][j] = (f32x4){0.f,0.f,0.f,0.f};
  for(int kb=0; kb<kchunk; kb+=64){
    __syncthreads();
    #pragma unroll
    for(int p=0;p<4;p++){
      int r = p*32 + (tid>>3), cb = tid&7;
      short8 va = *(const short8*)(A + (size_t)(m0+r)*lda + k0+kb + cb*8);
      short8 vb = *(const short8*)(B + (size_t)(n0+r)*ldb + k0+kb + cb*8);
      int off = r*128 + ((cb*16) ^ ((r&7)<<4));
      *(short8*)((char*)sA + off) = va;
      *(short8*)((char*)sB + off) = vb;
    }
    __syncthreads();
    #pragma unroll
    for(int ks=0;ks<2;ks++){
      short8 af[4], bfr[4];
      int kk = ks*32 + 8*(lane>>4);
      #pragma unroll
      for(int i=0;i<4;i++){
        af[i]  = frag64(sA, wr + i*16 + (lane&15), kk);
        bfr[i] = frag64(sB, wc + i*16 + (lane&15), kk);
      }
      #pragma unroll
      for(int i=0;i<4;i++)
        #pragma unroll
        for(int j=0;j<4;j++)
          acc[i][j] = MFMA16(af[i], bfr[j], acc[i][j]);
    }
  }
  const int rb = 4*(lane>>4), cb2 = lane&15;
  #pragma unroll
  for(int i=0;i<4;i++)
    #pragma unroll
    for(int j=0;j<4;j++){
      int col = n0 + wc + j*16 + cb2;
      #pragma unroll
      for(int r=0;r<4;r++){
        int row = m0 + wr + i*16 + rb + r;
        float v = acc[i][j][r];
        if(EPI==0){
          float* C = (float*)Cv;
          if(ATOMIC) atomicAdd(C + (size_t)row*ldc + col, v);
          else C[(size_t)row*ldc + col] = v;
        } else {
          float a = v>0.f ? v*v : 0.f;
          if(EPI==2) a *= (1.0f/1024.0f);
          if(EPI==3) a *= bf2f(aux[(size_t)row*ldaux + col]);
          ((u16*)Cv)[(size_t)row*ldc + col] = f2bf(a);
        }
      }
    }
}

// ---- RoPE ----
__global__ void k_rope(const u16* __restrict__ xs, const float* __restrict__ cosT,
                       const float* __restrict__ sinT, u16* __restrict__ q){
  int gidx = blockIdx.x*256 + threadIdx.x;   // T * 4096 half-pairs
  int t = gidx >> 12;
  int rem = gidx & 4095;
  int g = rem >> 7, c = rem & 127;
  size_t base = (size_t)t*HN + g*256;
  float x1 = bf2f(xs[base + c]), x2 = bf2f(xs[base + 128 + c]);
  float cs = cosT[t*128+c], sn = sinT[t*128+c];
  q[base + c]       = f2bf(x1*cs - x2*sn);
  q[base + 128 + c] = f2bf(x2*cs + x1*sn);
}

// ---- phase A: gate cumsum -> qg, kg, kS, exp(g_last). qg may alias q; kS may alias gate ----
__global__ void k_phase_a(const u16* q, const u16* gate, u16* qg, u16* kS, u16* kg, float* gle){
  int c = blockIdx.y;
  int j = blockIdx.x*256 + threadIdx.x;
  size_t base = (size_t)c*CHK*HN + j;
  float gsum = 0.f;
  for(int t=0;t<CHK;t++) gsum -= bf2f(gate[base + (size_t)t*HN]);
  float gc = 0.f;
  for(int t=0;t<CHK;t++){
    size_t ix = base + (size_t)t*HN;
    gc -= bf2f(gate[ix]);
    float qv = bf2f(q[ix]);
    qg[ix] = f2bf(qv * expf(gc) * SCALE_Q);
    kg[ix] = f2bf(qv * expf(-gc));
    kS[ix] = f2bf(qv * expf(gsum - gc));
  }
  gle[c*HN + j] = expf(gsum);
}

// ---- intra-chunk: A = qg@kg^T (masked), oT_init = vbT @ A^T ----
__global__ __launch_bounds__(256) void k_intra(const u16* __restrict__ qg, const u16* __restrict__ kg,
                                               const u16* __restrict__ xin_bf, float* __restrict__ oT){
  int c = blockIdx.x, h = blockIdx.y;
  int tid = threadIdx.x, lane = tid&63, wv = tid>>6;
  __shared__ __align__(16) u16 sQ[64*64], sK[64*64], sAm[64*64], sVT[256*64];
  ld_vbT(sVT, xin_bf + (size_t)c*CHK*DDIM, tid);
  f32x4 accA[4];
  #pragma unroll
  for(int j=0;j<4;j++) accA[j] = (f32x4){0.f,0.f,0.f,0.f};
  const u16* qbase = qg + (size_t)c*CHK*HN + h*NDIM;
  const u16* kbase = kg + (size_t)c*CHK*HN + h*NDIM;
  for(int kb=0;kb<NDIM;kb+=64){
    __syncthreads();
    ld_tile(sQ, qbase+kb, HN, tid);
    ld_tile(sK, kbase+kb, HN, tid);
    __syncthreads();
    #pragma unroll
    for(int ks=0;ks<2;ks++){
      int kk = ks*32 + 8*(lane>>4);
      short8 af = frag64(sQ, wv*16 + (lane&15), kk);
      #pragma unroll
      for(int j=0;j<4;j++){
        short8 bfr = frag64(sK, j*16 + (lane&15), kk);
        accA[j] = MFMA16(af, bfr, accA[j]);
      }
    }
  }
  __syncthreads();
  #pragma unroll
  for(int j=0;j<4;j++)
    #pragma unroll
    for(int r=0;r<4;r++){
      int t = wv*16 + 4*(lane>>4) + r, s = j*16 + (lane&15);
      float v = (s<=t)? accA[j][r] : 0.f;
      *(u16*)((char*)sAm + t*128 + ((s*2)^((t&7)<<4))) = f2bf(v);
    }
  __syncthreads();
  float* obase = oT + ((size_t)h*DDIM)*TLEN + (size_t)c*CHK;
  for(int ftc=0; ftc<4; ftc++){
    f32x4 acco[4];
    #pragma unroll
    for(int fd=0;fd<4;fd++) acco[fd] = (f32x4){0.f,0.f,0.f,0.f};
    #pragma unroll
    for(int ks=0;ks<2;ks++){
      int kk = ks*32 + 8*(lane>>4);
      short8 bfr = frag64(sAm, ftc*16 + (lane&15), kk);
      #pragma unroll
      for(int fd=0; fd<4; fd++){
        short8 af = frag64(sVT, wv*64 + fd*16 + (lane&15), kk);
        acco[fd] = MFMA16(af, bfr, acco[fd]);
      }
    }
    #pragma unroll
    for(int fd=0; fd<4; fd++)
      #pragma unroll
      for(int r=0;r<4;r++){
        int d = wv*64 + fd*16 + 4*(lane>>4)+r, t = ftc*16 + (lane&15);
        obase[(size_t)d*TLEN + t] = acco[fd][r];
      }
  }
}

// ---- recurrence: per-(h, n-block) WG, S in registers, chunk loop, no grid sync ----
__global__ __launch_bounds__(256) void k_recur(const u16* __restrict__ qg, const u16* __restrict__ kS,
                                               const u16* __restrict__ xin_bf, const float* __restrict__ gle,
                                               float* __restrict__ oT){
  int nb = blockIdx.x, h = blockIdx.y;
  int tid = threadIdx.x, lane = tid&63, wv = tid>>6;
  __shared__ __align__(16) u16 sQG[64*64], sKT[64*64], sVT[256*64], sS[256*64];
  f32x4 S[4][4];
  #pragma unroll
  for(int a=0;a<4;a++)
    #pragma unroll
    for(int b=0;b<4;b++) S[a][b] = (f32x4){0.f,0.f,0.f,0.f};
  for(int c=0;c<NCH;c++){
    __syncthreads();
    ld_tile (sQG, qg + (size_t)c*CHK*HN + h*NDIM + nb*64, HN, tid);
    ld_tileT(sKT, kS + (size_t)c*CHK*HN + h*NDIM + nb*64, HN, tid);
    ld_vbT  (sVT, xin_bf + (size_t)c*CHK*DDIM, tid);
    if(c>0){
      #pragma unroll
      for(int fd=0;fd<4;fd++)
        #pragma unroll
        for(int fn=0;fn<4;fn++)
          #pragma unroll
          for(int r=0;r<4;r++){
            int d = wv*64 + fd*16 + 4*(lane>>4)+r, n = fn*16 + (lane&15);
            *(u16*)((char*)sS + d*128 + ((n*2)^((d&7)<<4))) = f2bf(S[fd][fn][r]);
          }
    }
    __syncthreads();
    if(c>0){
      float* obase = oT + ((size_t)h*DDIM + wv*64)*TLEN + (size_t)c*CHK;
      for(int ft=0; ft<4; ft++){
        f32x4 acco[4];
        #pragma unroll
        for(int fd=0;fd<4;fd++) acco[fd] = (f32x4){0.f,0.f,0.f,0.f};
        #pragma unroll
        for(int ks=0;ks<2;ks++){
          int kk = ks*32 + 8*(lane>>4);
          short8 bfr = frag64(sQG, ft*16 + (lane&15), kk);
          #pragma unroll
          for(int fd=0; fd<4; fd++){
            short8 af = frag64(sS, wv*64 + fd*16 + (lane&15), kk);
            acco[fd] = MFMA16(af, bfr, acco[fd]);
          }
        }
        #pragma unroll
        for(int fd=0; fd<4; fd++)
          #pragma unroll
          for(int r=0;r<4;r++){
            int d = fd*16 + 4*(lane>>4)+r, t = ft*16 + (lane&15);
            atomicAdd(obase + (size_t)d*TLEN + t, acco[fd][r]);
          }
      }
    }
    const float* gbase = gle + (size_t)c*HN + h*NDIM + nb*64;
    #pragma unroll
    for(int fn=0; fn<4; fn++){
      float gv = gbase[fn*16 + (lane&15)];
      #pragma unroll
      for(int fd=0; fd<4; fd++){
        S[fd][fn][0]*=gv; S[fd][fn][1]*=gv; S[fd][fn][2]*=gv; S[fd][fn][3]*=gv;
      }
    }
    #pragma unroll
    for(int ks=0;ks<2;ks++){
      int kk = ks*32 + 8*(lane>>4);
      short8 afv[4], bfk[4];
      #pragma unroll
      for(int fd=0;fd<4;fd++) afv[fd] = frag64(sVT, wv*64 + fd*16 + (lane&15), kk);
      #pragma unroll
      for(int fn=0;fn<4;fn++) bfk[fn] = frag64(sKT, fn*16 + (lane&15), kk);
      #pragma unroll
      for(int fd=0;fd<4;fd++)
        #pragma unroll
        for(int fn=0;fn<4;fn++)
          S[fd][fn] = MFMA16(afv[fd], bfk[fn], S[fd][fn]);
    }
  }
}

// ---- layernorm over d of oT[h][d][t] -> oln[h][t][d] bf16 ----
__global__ __launch_bounds__(256) void k_lnorm(const float* __restrict__ oT, u16* __restrict__ oln){
  int tb = blockIdx.x, h = blockIdx.y;
  int tid = threadIdx.x, lane = tid&63, wv = tid>>6;
  __shared__ float ld[64][261];
  for(int p=0;p<64;p++){
    int idx = p*256+tid; int d = idx>>6, tt = idx&63;
    ld[tt][d] = oT[((size_t)h*DDIM + d)*TLEN + tb*64 + tt];
  }
  __syncthreads();
  for(int i=0;i<16;i++){
    int tt = wv*16 + i;
    float v[4]; float s1=0.f, s2=0.f;
    #pragma unroll
    for(int j=0;j<4;j++){ v[j] = ld[tt][lane + j*64]; s1+=v[j]; s2+=v[j]*v[j]; }
    s1 = wave_sum(s1); s2 = wave_sum(s2);
    float m = s1*(1.0f/DDIM), var = s2*(1.0f/DDIM) - m*m;
    float rs = rsqrtf(var + 1e-5f);
    size_t base = ((size_t)h*TLEN + tb*64 + tt)*DDIM;
    #pragma unroll
    for(int j=0;j<4;j++) oln[base + lane + j*64] = f2bf((v[j]-m)*rs);
  }
}

// ---- dec epilogue: layernorm(yraw) + xin, then rmsnorm -> x ----
__global__ __launch_bounds__(256) void k_post(const float* yraw, const float* xin, float* x){
  __shared__ float tmp[4];
  int t = blockIdx.x, d = threadIdx.x;
  float v = yraw[t*DDIM+d];
  float s1 = block_sum(v, tmp);
  float m = s1*(1.0f/DDIM);
  float cvt = v - m;
  float s2 = block_sum(cvt*cvt, tmp);
  float y = cvt * rsqrtf(s2*(1.0f/DDIM) + 1e-5f);
  float xn = y + xin[t*DDIM+d];
  float s3 = block_sum(xn*xn, tmp);
  x[t*DDIM+d] = xn * rsqrtf(s3*(1.0f/DDIM) + 1e-5f);
}

__global__ __launch_bounds__(256) void k_final(const float* x, const float* x0, const float* bl, u16* xf){
  __shared__ float tmp[4];
  int t = blockIdx.x, d = threadIdx.x;
  float v = x[t*DDIM+d] - bl[0]*x0[t*DDIM+d];
  float s = block_sum(v*v, tmp);
  xf[t*DDIM+d] = f2bf(v * rsqrtf(s*(1.0f/DDIM) + 1e-5f));
}

extern "C" void kernel_launch(void* const* d_in, const int* in_sizes, int n_in,
                              void* d_out, int out_size, void* d_ws, size_t ws_size,
                              hipStream_t stream){
  (void)in_sizes; (void)n_in; (void)out_size; (void)ws_size;
  const float* embed_w = (const float*)d_in[0];
  const float* lm_w    = (const float*)d_in[1];
  const float* enc_w   = (const float*)d_in[2];
  const float* gate_w  = (const float*)d_in[3];
  const float* dec_w   = (const float*)d_in[4];
  const float* encv_w  = (const float*)d_in[5];
  const float* backout = (const float*)d_in[6];
  const float* rlam    = (const float*)d_in[7];
  const float* xlam    = (const float*)d_in[8];
  const int*   idx     = (const int*)d_in[9];
  float* out = (float*)d_out;

  char* p = (char*)d_ws;
  auto alloc = [&](size_t b)->char*{ char* r=p; p += (b+255)&~(size_t)255; return r; };
  float* cosT = (float*)alloc((size_t)TLEN*128*4);
  float* sinT = (float*)alloc((size_t)TLEN*128*4);
  float* x    = (float*)alloc((size_t)TLEN*DDIM*4);
  float* x0   = (float*)alloc((size_t)TLEN*DDIM*4);
  float* xin  = (float*)alloc((size_t)TLEN*DDIM*4);
  u16* xin_bf = (u16*)alloc((size_t)TLEN*DDIM*2);
  u16* xs     = (u16*)alloc((size_t)TLEN*HN*2);
  u16* gate   = (u16*)alloc((size_t)TLEN*HN*2);   // later aliased as kS
  u16* q      = (u16*)alloc((size_t)TLEN*HN*2);   // later aliased as qg, then xy
  u16* kg     = (u16*)alloc((size_t)TLEN*HN*2);
  float* gle  = (float*)alloc((size_t)NCH*HN*4);
  float* oT   = (float*)alloc((size_t)NH_*DDIM*TLEN*4);
  u16* oln    = (u16*)alloc((size_t)NH_*TLEN*DDIM*2);
  float* yraw = (float*)alloc((size_t)TLEN*DDIM*4);
  u16* xf     = (u16*)alloc((size_t)TLEN*DDIM*2);
  u16* w_enc  = (u16*)alloc((size_t)HN*DDIM*2);
  u16* w_gate = (u16*)alloc((size_t)HN*DDIM*2);
  u16* w_dec  = (u16*)alloc((size_t)DDIM*HN*2);
  u16* w_encv = (u16*)alloc((size_t)NH_*NDIM*DDIM*2);
  u16* w_lm   = (u16*)alloc((size_t)VP_*DDIM*2);

  k_tables<<<TLEN,128,0,stream>>>(cosT,sinT);
  k_cvt<<<2048,256,0,stream>>>(enc_w,  w_enc,  HN*DDIM);
  k_cvt<<<2048,256,0,stream>>>(gate_w, w_gate, HN*DDIM);
  k_cvt<<<2048,256,0,stream>>>(dec_w,  w_dec,  DDIM*HN);
  k_cvt<<<2048,256,0,stream>>>(encv_w, w_encv, NH_*NDIM*DDIM);
  k_cvt<<<4096,256,0,stream>>>(lm_w,   w_lm,   VP_*DDIM);
  k_embed<<<TLEN,256,0,stream>>>(embed_w, idx, x, x0);

  for(int li=0; li<4; li++){
    k_xin<<<TLEN,256,0,stream>>>(x,x0,rlam,xlam,li,xin,xin_bf,yraw);
    // xs = sqrelu(xin @ enc_w^T)
    k_gemm<1,false><<<dim3(8,64),256,0,stream>>>(xin_bf,DDIM,w_enc,DDIM,(void*)xs,HN,nullptr,0,DDIM);
    // gate = sqrelu(xin @ gate_w^T)/1024
    k_gemm<2,false><<<dim3(8,64),256,0,stream>>>(xin_bf,DDIM,w_gate,DDIM,(void*)gate,HN,nullptr,0,DDIM);
    k_rope<<<TLEN*4096/256,256,0,stream>>>(xs,cosT,sinT,q);
    k_phase_a<<<dim3(32,NCH),256,0,stream>>>(q,gate,/*qg=*/q,/*kS=*/gate,kg,gle);
    k_intra<<<dim3(NCH,NH_),256,0,stream>>>(/*qg=*/q,kg,xin_bf,oT);
    k_recur<<<dim3(32,NH_),256,0,stream>>>(/*qg=*/q,/*kS=*/gate,xin_bf,gle,oT);
    k_lnorm<<<dim3(16,NH_),256,0,stream>>>(oT,oln);
    // xy = xs * sqrelu(oln @ encv^T), per head; xy aliases q (qg dead)
    for(int h=0;h<4;h++)
      k_gemm<3,false><<<dim3(8,16),256,0,stream>>>(
        oln + (size_t)h*TLEN*DDIM, DDIM, w_encv + (size_t)h*NDIM*DDIM, DDIM,
        (void*)(q + h*NDIM), HN, xs + h*NDIM, HN, DDIM);
    // yraw = xy @ dec_w^T (split-K atomic; yraw zeroed in k_xin)
    k_gemm<0,true><<<dim3(8,2,8),256,0,stream>>>(q,HN,w_dec,HN,(void*)yraw,DDIM,nullptr,0,1024);
    k_post<<<TLEN,256,0,stream>>>(yraw,xin,x);
  }
  k_final<<<TLEN,256,0,stream>>>(x,x0,backout,xf);
  k_gemm<0,false><<<dim3(8,393),256,0,stream>>>(xf,DDIM,w_lm,DDIM,(void*)out,VP_,nullptr,0,DDIM);
}

// Round 4
// 1249.500 us; speedup vs baseline: 1.5385x; 1.5385x over previous
//
#include <hip/hip_runtime.h>
#include <math.h>

#define TLEN 1024
#define DDIM 256
#define NH_  4
#define NDIM 2048
#define HN   8192
#define NCH  16
#define CHK  64
#define VP_  50304
#define SCALE_Q 0.022097086912079608f  // 2048^-0.5

typedef unsigned short u16;
typedef __attribute__((ext_vector_type(8))) short short8;
typedef __attribute__((ext_vector_type(4))) float f32x4;

#define MFMA16(a,b,c) __builtin_amdgcn_mfma_f32_16x16x32_bf16((a),(b),(c),0,0,0)

__device__ __forceinline__ float bf2f(u16 u){ return __uint_as_float(((unsigned)u)<<16); }
__device__ __forceinline__ u16 f2bf(float f){
  unsigned x = __float_as_uint(f);
  return (u16)((x + 0x7fffu + ((x>>16)&1u)) >> 16);
}
__device__ __forceinline__ float wave_sum(float v){
  #pragma unroll
  for(int o=1;o<64;o<<=1) v += __shfl_xor(v,o,64);
  return v;
}
__device__ __forceinline__ float block_sum(float v, float* tmp){
  v = wave_sum(v);
  __syncthreads();
  if((threadIdx.x&63)==0) tmp[threadIdx.x>>6]=v;
  __syncthreads();
  return tmp[0]+tmp[1]+tmp[2]+tmp[3];
}

// ---- LDS tile helpers: 64-col bf16 tiles, rows 128B, XOR-swizzled 16B slots ----
__device__ __forceinline__ void ld_tile(u16* dst, const u16* src, int ldg, int tid){
  #pragma unroll
  for(int p=0;p<2;p++){
    int r = p*32 + (tid>>3), cb = tid&7;
    short8 v = *(const short8*)(src + (size_t)r*ldg + cb*8);
    *(short8*)((char*)dst + r*128 + ((cb*16) ^ ((r&7)<<4))) = v;
  }
}
// dst[col][row] = src[row][col]  (64x64), scalar transpose writes
__device__ __forceinline__ void ld_tileT(u16* dst, const u16* src, int ldg, int tid){
  #pragma unroll
  for(int p=0;p<2;p++){
    int idx = p*256 + tid; int t = idx>>3, cb = idx&7;
    short8 v = *(const short8*)(src + (size_t)t*ldg + cb*8);
    #pragma unroll
    for(int j=0;j<8;j++){
      int n = cb*8+j;
      *(u16*)((char*)dst + n*128 + ((t*2) ^ ((n&7)<<4))) = (u16)v[j];
    }
  }
}
__device__ __forceinline__ short8 frag64(const u16* lds, int row, int k){
  return *(const short8*)((const char*)lds + row*128 + ((k*2) ^ ((row&7)<<4)));
}

// ---- setup kernels ----
__global__ void k_tables(float* cosT, float* sinT){
  int t = blockIdx.x, i = threadIdx.x; // 128 threads
  float inv_freq = exp2f(-18.0f * (float)(2*i) * (1.0f/256.0f));
  float fr = (float)t * inv_freq;
  float xsc = ((float)(2*i) + 102.4f) * (1.0f/358.4f);
  float power = ((float)t - 512.0f) * (1.0f/512.0f);
  float sc = exp2f(power * log2f(xsc));
  cosT[t*128+i] = cosf(fr)*sc;
  sinT[t*128+i] = sinf(fr)*sc;
}
__global__ void k_cvt(const float* in, u16* out, int n){
  for(int i = blockIdx.x*blockDim.x + threadIdx.x; i < n; i += gridDim.x*blockDim.x)
    out[i] = f2bf(in[i]);
}
__global__ __launch_bounds__(256) void k_embed(const float* emb, const int* idx, float* x, float* x0){
  __shared__ float tmp[4];
  int t = blockIdx.x, d = threadIdx.x;
  float v = emb[(size_t)idx[t]*DDIM + d];
  float s = block_sum(v*v, tmp);
  float o = v * rsqrtf(s*(1.0f/DDIM) + 1e-5f);
  x[t*DDIM+d]=o; x0[t*DDIM+d]=o;
}
__global__ void k_xin(const float* x, const float* x0, const float* rl, const float* xl, int li,
                      float* xin, u16* xin_bf, float* yraw){
  int i = blockIdx.x*256 + threadIdx.x;
  float v = rl[li]*x[i] + xl[li]*x0[i];
  xin[i]=v; xin_bf[i]=f2bf(v); yraw[i]=0.f;
}

// ---- generic bf16 GEMM: C = epi(A(MxK) @ B(NxK)^T) ----
// EPI: 0=fp32 store(/atomic), 1=sqrelu->bf16, 2=sqrelu/1024->bf16, 3=aux*sqrelu->bf16
template<int EPI, bool ATOMIC>
__global__ __launch_bounds__(256) void k_gemm(
  const u16* __restrict__ A, int lda, const u16* __restrict__ B, int ldb,
  void* Cv, int ldc, const u16* __restrict__ aux, int ldaux, int kchunk)
{
  __shared__ __align__(16) u16 sA[128*64];
  __shared__ __align__(16) u16 sB[128*64];
  const int m0 = blockIdx.x*128, n0 = blockIdx.y*128;
  const int k0 = blockIdx.z*kchunk;
  const int tid = threadIdx.x, lane = tid&63, wv = tid>>6;
  const int wr = (wv>>1)*64, wc = (wv&1)*64;
  f32x4 acc[4][4];
  #pragma unroll
  for(int i=0;i<4;i++)
    #pragma unroll
    for(int j=0;j<4;j++) acc[i][j] = (f32x4){0.f,0.f,0.f,0.f};
  for(int kb=0; kb<kchunk; kb+=64){
    __syncthreads();
    #pragma unroll
    for(int p=0;p<4;p++){
      int r = p*32 + (tid>>3), cb = tid&7;
      short8 va = *(const short8*)(A + (size_t)(m0+r)*lda + k0+kb + cb*8);
      short8 vb = *(const short8*)(B + (size_t)(n0+r)*ldb + k0+kb + cb*8);
      int off = r*128 + ((cb*16) ^ ((r&7)<<4));
      *(short8*)((char*)sA + off) = va;
      *(short8*)((char*)sB + off) = vb;
    }
    __syncthreads();
    #pragma unroll
    for(int ks=0;ks<2;ks++){
      short8 af[4], bfr[4];
      int kk = ks*32 + 8*(lane>>4);
      #pragma unroll
      for(int i=0;i<4;i++){
        af[i]  = frag64(sA, wr + i*16 + (lane&15), kk);
        bfr[i] = frag64(sB, wc + i*16 + (lane&15), kk);
      }
      #pragma unroll
      for(int i=0;i<4;i++)
        #pragma unroll
        for(int j=0;j<4;j++)
          acc[i][j] = MFMA16(af[i], bfr[j], acc[i][j]);
    }
  }
  const int rb = 4*(lane>>4), cb2 = lane&15;
  #pragma unroll
  for(int i=0;i<4;i++)
    #pragma unroll
    for(int j=0;j<4;j++){
      int col = n0 + wc + j*16 + cb2;
      #pragma unroll
      for(int r=0;r<4;r++){
        int row = m0 + wr + i*16 + rb + r;
        float v = acc[i][j][r];
        if(EPI==0){
          float* C = (float*)Cv;
          if(ATOMIC) atomicAdd(C + (size_t)row*ldc + col, v);
          else C[(size_t)row*ldc + col] = v;
        } else {
          float a = v>0.f ? v*v : 0.f;
          if(EPI==2) a *= (1.0f/1024.0f);
          if(EPI==3) a *= bf2f(aux[(size_t)row*ldaux + col]);
          ((u16*)Cv)[(size_t)row*ldc + col] = f2bf(a);
        }
      }
    }
}

// ---- RoPE ----
__global__ void k_rope(const u16* __restrict__ xs, const float* __restrict__ cosT,
                       const float* __restrict__ sinT, u16* __restrict__ q){
  int gidx = blockIdx.x*256 + threadIdx.x;   // T * 4096 half-pairs
  int t = gidx >> 12;
  int rem = gidx & 4095;
  int g = rem >> 7, c = rem & 127;
  size_t base = (size_t)t*HN + g*256;
  float x1 = bf2f(xs[base + c]), x2 = bf2f(xs[base + 128 + c]);
  float cs = cosT[t*128+c], sn = sinT[t*128+c];
  q[base + c]       = f2bf(x1*cs - x2*sn);
  q[base + 128 + c] = f2bf(x2*cs + x1*sn);
}

// ---- phase A: gate cumsum -> qg (in-place on q), kgT[c][h][n][t], gle ----
__global__ void k_phase_a(const u16* __restrict__ q, const u16* __restrict__ gate,
                          u16* __restrict__ qg, u16* __restrict__ kgT, float* __restrict__ gle){
  int c = blockIdx.y;
  int j = blockIdx.x*256 + threadIdx.x;
  int h = j>>11, n = j&2047;
  size_t base = (size_t)c*CHK*HN + j;
  float gsum = 0.f;
  #pragma unroll
  for(int t=0;t<CHK;t++) gsum -= bf2f(gate[base + (size_t)t*HN]);
  float egsum = expf(gsum);
  u16 kv[64];
  float gc = 0.f;
  #pragma unroll
  for(int t=0;t<CHK;t++){
    size_t ix = base + (size_t)t*HN;
    gc -= bf2f(gate[ix]);
    float qv = bf2f(q[ix]);
    float e1 = expf(gc);
    float ei = 1.0f/e1;
    qg[ix] = f2bf(qv * e1 * SCALE_Q);
    kv[t]  = f2bf(qv * ei);              // kg value
  }
  u16* kb = kgT + (((size_t)c*NH_ + h)*NDIM + n)*CHK;
  #pragma unroll
  for(int p=0;p<8;p++){
    short8 v;
    #pragma unroll
    for(int e=0;e<8;e++) v[e] = (short)kv[p*8+e];
    *(short8*)(kb + p*8) = v;
  }
  gle[(size_t)c*HN + j] = egsum;
}

// ---- vbT[c][d][t] = xin_bf[c*64+t][d] ----
__global__ __launch_bounds__(256) void k_vbt(const u16* __restrict__ xin_bf, u16* __restrict__ vbT){
  int c = blockIdx.x, tid = threadIdx.x;
  __shared__ u16 s[64*DDIM];
  #pragma unroll
  for(int p=0;p<8;p++){
    int idx = p*256+tid; int t = idx>>5, cb = idx&31;
    *(short8*)(s + t*DDIM + cb*8) = *(const short8*)(xin_bf + ((size_t)c*CHK + t)*DDIM + cb*8);
  }
  __syncthreads();
  int d = tid;
  u16 col[64];
  #pragma unroll
  for(int t=0;t<64;t++) col[t] = s[t*DDIM + d];
  u16* dst = vbT + ((size_t)c*DDIM + d)*CHK;
  #pragma unroll
  for(int p=0;p<8;p++){
    short8 v;
    #pragma unroll
    for(int e=0;e<8;e++) v[e] = (short)col[p*8+e];
    *(short8*)(dst + p*8) = v;
  }
}

// ---- A matrices: Aall[c][h][t][s] = mask(qg@kg^T), bf16. kg supplied transposed. ----
__global__ __launch_bounds__(256) void k_qk(const u16* __restrict__ qg, const u16* __restrict__ kgT,
                                            u16* __restrict__ Aall){
  int c = blockIdx.x, h = blockIdx.y;
  int tid = threadIdx.x, lane = tid&63, wv = tid>>6;
  __shared__ __align__(16) u16 sQ[2][64*64], sK[2][64*64], sAm[64*64];
  const u16* qb = qg + (size_t)c*CHK*HN + h*NDIM;
  const u16* kb = kgT + ((size_t)c*NH_ + h)*NDIM*CHK;
  f32x4 accA[4];
  #pragma unroll
  for(int j=0;j<4;j++) accA[j] = (f32x4){0.f,0.f,0.f,0.f};
  ld_tile (sQ[0], qb, HN, tid);
  ld_tileT(sK[0], kb, CHK, tid);   // sK[s][n] = kg[s][n]
  __syncthreads();
  for(int kt=0; kt<32; kt++){
    if(kt<31){
      ld_tile (sQ[(kt+1)&1], qb + (kt+1)*64, HN, tid);
      ld_tileT(sK[(kt+1)&1], kb + (size_t)(kt+1)*64*CHK, CHK, tid);
    }
    #pragma unroll
    for(int kh=0;kh<2;kh++){
      int kk = kh*32 + 8*(lane>>4);
      short8 af = frag64(sQ[kt&1], wv*16 + (lane&15), kk);
      #pragma unroll
      for(int j=0;j<4;j++){
        short8 b = frag64(sK[kt&1], j*16 + (lane&15), kk);
        accA[j] = MFMA16(af, b, accA[j]);
      }
    }
    __syncthreads();
  }
  #pragma unroll
  for(int j=0;j<4;j++)
    #pragma unroll
    for(int r=0;r<4;r++){
      int t = wv*16 + 4*(lane>>4) + r, s = j*16 + (lane&15);
      float v = (s<=t)? accA[j][r] : 0.f;
      *(u16*)((char*)sAm + t*128 + ((s*2)^((t&7)<<4))) = f2bf(v);
    }
  __syncthreads();
  #pragma unroll
  for(int p=0;p<2;p++){           // FIXED: full 64x64 store (2 slots/thread)
    int ii = p*256 + tid;
    int tl = ii>>3, seg = ii&7;
    short8 v8 = frag64(sAm, tl, seg*8);
    *(short8*)(Aall + (((size_t)c*NH_ + h)*CHK + tl)*CHK + seg*8) = v8;
  }
}

// ---- pass 1 (per n-half): boundary states ST[c][h][d][n_half], c=0..14 ----
__global__ __launch_bounds__(256) void k_state(const u16* __restrict__ kgT, const u16* __restrict__ vbT,
                                               const float* __restrict__ gle, u16* __restrict__ ST, int half){
  int nb = blockIdx.x, db = blockIdx.y, h = blockIdx.z;   // nb in 0..15 within half
  int tid = threadIdx.x, lane = tid&63, wv = tid>>6;
  __shared__ __align__(16) u16 sK[64*64], sV[64*64], sD[64*64];
  int ng = half*1024 + nb*64;
  f32x4 S[4];
  #pragma unroll
  for(int fn=0;fn<4;fn++) S[fn] = (f32x4){0.f,0.f,0.f,0.f};
  for(int c=0;c<15;c++){
    __syncthreads();
    ld_tile(sK, kgT + (((size_t)c*NH_ + h)*NDIM + ng)*CHK, CHK, tid);   // rows n, cols t
    ld_tile(sV, vbT + ((size_t)c*DDIM + db*64)*CHK, CHK, tid);          // rows d, cols t
    __syncthreads();
    // S += U  (U[d][n] = sum_t vb[t][d]*kg[t][n]), then S *= e^{g_last}[n]
    #pragma unroll
    for(int kh=0;kh<2;kh++){
      int kk = kh*32 + 8*(lane>>4);
      short8 af = frag64(sV, wv*16 + (lane&15), kk);
      #pragma unroll
      for(int fn=0;fn<4;fn++){
        short8 b = frag64(sK, fn*16 + (lane&15), kk);
        S[fn] = MFMA16(af, b, S[fn]);
      }
    }
    #pragma unroll
    for(int fn=0;fn<4;fn++){
      float gv = gle[(size_t)c*HN + h*NDIM + ng + fn*16 + (lane&15)];
      S[fn][0]*=gv; S[fn][1]*=gv; S[fn][2]*=gv; S[fn][3]*=gv;
    }
    __syncthreads();
    #pragma unroll
    for(int fn=0;fn<4;fn++)
      #pragma unroll
      for(int r=0;r<4;r++){
        int d = wv*16 + 4*(lane>>4) + r, n = fn*16 + (lane&15);
        *(u16*)((char*)sD + d*128 + ((n*2)^((d&7)<<4))) = f2bf(S[fn][r]);
      }
    __syncthreads();
    #pragma unroll
    for(int p=0;p<2;p++){         // FIXED: full 64x64 store (2 slots/thread)
      int ii = p*256 + tid;
      int dl = ii>>3, seg = ii&7;
      short8 v = frag64(sD, dl, seg*8);
      *(short8*)(ST + (((size_t)c*NH_ + h)*DDIM + db*64 + dl)*1024 + nb*64 + seg*8) = v;
    }
  }
}

// ---- pass 2a: o[h][t][d] = Amask @ vb  (init store) ----
__global__ __launch_bounds__(256) void k_out_intra(const u16* __restrict__ Aall, const u16* __restrict__ vbT,
                                                   float* __restrict__ o){
  int c = blockIdx.x, h = blockIdx.y, db = blockIdx.z;
  int tid = threadIdx.x, lane = tid&63, wv = tid>>6;
  __shared__ __align__(16) u16 sA[64*64], sV[64*64];
  ld_tile(sA, Aall + ((size_t)c*NH_ + h)*CHK*CHK, CHK, tid);
  ld_tile(sV, vbT + ((size_t)c*DDIM + db*64)*CHK, CHK, tid);
  f32x4 acc[4];
  #pragma unroll
  for(int j=0;j<4;j++) acc[j] = (f32x4){0.f,0.f,0.f,0.f};
  __syncthreads();
  #pragma unroll
  for(int kh=0;kh<2;kh++){
    int kk = kh*32 + 8*(lane>>4);
    short8 af = frag64(sA, wv*16 + (lane&15), kk);
    #pragma unroll
    for(int j=0;j<4;j++){
      short8 b = frag64(sV, j*16 + (lane&15), kk);
      acc[j] = MFMA16(af, b, acc[j]);
    }
  }
  int rb = 4*(lane>>4), cl = lane&15;
  #pragma unroll
  for(int j=0;j<4;j++){
    int d = db*64 + j*16 + cl;
    #pragma unroll
    for(int r=0;r<4;r++){
      int t = c*CHK + wv*16 + rb + r;
      o[((size_t)h*TLEN + t)*DDIM + d] = acc[j][r];
    }
  }
}

// ---- pass 2b (per n-half): o[h][t][d] += qg[:,half] @ ST_{c-1} ----
__global__ __launch_bounds__(256) void k_out_inter(const u16* __restrict__ qg, const u16* __restrict__ ST,
                                                   float* __restrict__ o, int half){
  int c = blockIdx.x + 1, h = blockIdx.y, db = blockIdx.z;
  int tid = threadIdx.x, lane = tid&63, wv = tid>>6;
  __shared__ __align__(16) u16 sQ[2][64*64];
  f32x4 acc[4];
  #pragma unroll
  for(int j=0;j<4;j++) acc[j] = (f32x4){0.f,0.f,0.f,0.f};
  const u16* stb = ST + (((size_t)(c-1)*NH_ + h)*DDIM + db*64)*1024;
  const u16* qb  = qg + (size_t)c*CHK*HN + h*NDIM + half*1024;
  ld_tile(sQ[0], qb, HN, tid);
  short8 bn[8];
  #pragma unroll
  for(int u=0;u<8;u++)
    bn[u] = *(const short8*)(stb + (size_t)((u&3)*16 + (lane&15))*1024 + (u>>2)*32 + 8*(lane>>4));
  __syncthreads();
  for(int kt=0; kt<16; kt++){
    short8 bc[8];
    #pragma unroll
    for(int u=0;u<8;u++) bc[u] = bn[u];
    if(kt<15){
      #pragma unroll
      for(int u=0;u<8;u++)
        bn[u] = *(const short8*)(stb + (size_t)((u&3)*16 + (lane&15))*1024 + (kt+1)*64 + (u>>2)*32 + 8*(lane>>4));
      ld_tile(sQ[(kt+1)&1], qb + (kt+1)*64, HN, tid);
    }
    #pragma unroll
    for(int kh=0;kh<2;kh++){
      int kk = kh*32 + 8*(lane>>4);
      short8 af = frag64(sQ[kt&1], wv*16 + (lane&15), kk);
      #pragma unroll
      for(int j=0;j<4;j++) acc[j] = MFMA16(af, bc[kh*4+j], acc[j]);
    }
    __syncthreads();
  }
  int rb = 4*(lane>>4), cl = lane&15;
  #pragma unroll
  for(int j=0;j<4;j++){
    int d = db*64 + j*16 + cl;
    #pragma unroll
    for(int r=0;r<4;r++){
      int t = c*CHK + wv*16 + rb + r;
      size_t ix = ((size_t)h*TLEN + t)*DDIM + d;
      o[ix] += acc[j][r];
    }
  }
}

// ---- layernorm over d of o[h][t][d] -> oln[h][t][d] bf16 ----
__global__ __launch_bounds__(256) void k_ln(const float* __restrict__ o, u16* __restrict__ oln){
  __shared__ float tmp[4];
  int t = blockIdx.x, h = blockIdx.y, d = threadIdx.x;
  size_t ix = ((size_t)h*TLEN + t)*DDIM + d;
  float v = o[ix];
  float s1 = block_sum(v, tmp);
  float m = s1*(1.0f/DDIM);
  float cv = v - m;
  float s2 = block_sum(cv*cv, tmp);
  oln[ix] = f2bf(cv * rsqrtf(s2*(1.0f/DDIM) + 1e-5f));
}

// ---- dec epilogue: layernorm(yraw) + xin, then rmsnorm -> x ----
__global__ __launch_bounds__(256) void k_post(const float* yraw, const float* xin, float* x){
  __shared__ float tmp[4];
  int t = blockIdx.x, d = threadIdx.x;
  float v = yraw[t*DDIM+d];
  float s1 = block_sum(v, tmp);
  float m = s1*(1.0f/DDIM);
  float cvt = v - m;
  float s2 = block_sum(cvt*cvt, tmp);
  float y = cvt * rsqrtf(s2*(1.0f/DDIM) + 1e-5f);
  float xn = y + xin[t*DDIM+d];
  float s3 = block_sum(xn*xn, tmp);
  x[t*DDIM+d] = xn * rsqrtf(s3*(1.0f/DDIM) + 1e-5f);
}

__global__ __launch_bounds__(256) void k_final(const float* x, const float* x0, const float* bl, u16* xf){
  __shared__ float tmp[4];
  int t = blockIdx.x, d = threadIdx.x;
  float v = x[t*DDIM+d] - bl[0]*x0[t*DDIM+d];
  float s = block_sum(v*v, tmp);
  xf[t*DDIM+d] = f2bf(v * rsqrtf(s*(1.0f/DDIM) + 1e-5f));
}

extern "C" void kernel_launch(void* const* d_in, const int* in_sizes, int n_in,
                              void* d_out, int out_size, void* d_ws, size_t ws_size,
                              hipStream_t stream){
  (void)in_sizes; (void)n_in; (void)out_size; (void)ws_size;
  const float* embed_w = (const float*)d_in[0];
  const float* lm_w    = (const float*)d_in[1];
  const float* enc_w   = (const float*)d_in[2];
  const float* gate_w  = (const float*)d_in[3];
  const float* dec_w   = (const float*)d_in[4];
  const float* encv_w  = (const float*)d_in[5];
  const float* backout = (const float*)d_in[6];
  const float* rlam    = (const float*)d_in[7];
  const float* xlam    = (const float*)d_in[8];
  const int*   idx     = (const int*)d_in[9];
  float* out = (float*)d_out;

  // ---- workspace layout: ~107.5 MB total (round-2's 117.7 MB layout passed) ----
  char* p = (char*)d_ws;
  auto alloc = [&](size_t b)->char*{ char* r=p; p += (b+255)&~(size_t)255; return r; };
  float* cosT = (float*)alloc((size_t)TLEN*128*4);
  float* sinT = (float*)alloc((size_t)TLEN*128*4);
  float* x    = (float*)alloc((size_t)TLEN*DDIM*4);
  float* x0   = (float*)alloc((size_t)TLEN*DDIM*4);
  float* xin  = (float*)alloc((size_t)TLEN*DDIM*4);
  u16* xin_bf = (u16*)alloc((size_t)TLEN*DDIM*2);
  u16* xs     = (u16*)alloc((size_t)TLEN*HN*2);        // 16 MB
  u16* q      = (u16*)alloc((size_t)TLEN*HN*2);        // 16 MB: qg in-place, later xy
  u16* gate   = (u16*)alloc((size_t)TLEN*HN*2);        // 16 MB; dead after phase_a
  (void)alloc((size_t)15*NH_*DDIM*1024*2 - (size_t)TLEN*HN*2);  // ST extension (14 MB)
  u16* ST     = gate;   // 30 MB region = gate + extension; live only state->out_inter
  u16* w_lm   = gate;   // 25.7 MB region; used after layer loop only
  u16* kgT    = (u16*)alloc((size_t)NCH*NH_*NDIM*CHK*2); // 16 MB
  float* gle  = (float*)alloc((size_t)NCH*HN*4);
  u16* vbT    = (u16*)alloc((size_t)NCH*DDIM*CHK*2);
  u16* Aall   = (u16*)alloc((size_t)NCH*NH_*CHK*CHK*2);
  float* o    = (float*)alloc((size_t)NH_*TLEN*DDIM*4);  // 4 MB
  u16* oln    = (u16*)alloc((size_t)NH_*TLEN*DDIM*2);
  float* yraw = (float*)alloc((size_t)TLEN*DDIM*4);
  u16* xf     = (u16*)alloc((size_t)TLEN*DDIM*2);
  u16* w_enc  = (u16*)alloc((size_t)HN*DDIM*2);
  u16* w_gate = (u16*)alloc((size_t)HN*DDIM*2);
  u16* w_dec  = (u16*)alloc((size_t)DDIM*HN*2);
  u16* w_encv = (u16*)alloc((size_t)NH_*NDIM*DDIM*2);

  k_tables<<<TLEN,128,0,stream>>>(cosT,sinT);
  k_cvt<<<2048,256,0,stream>>>(enc_w,  w_enc,  HN*DDIM);
  k_cvt<<<2048,256,0,stream>>>(gate_w, w_gate, HN*DDIM);
  k_cvt<<<2048,256,0,stream>>>(dec_w,  w_dec,  DDIM*HN);
  k_cvt<<<2048,256,0,stream>>>(encv_w, w_encv, NH_*NDIM*DDIM);
  k_embed<<<TLEN,256,0,stream>>>(embed_w, idx, x, x0);

  for(int li=0; li<4; li++){
    k_xin<<<TLEN,256,0,stream>>>(x,x0,rlam,xlam,li,xin,xin_bf,yraw);
    k_gemm<1,false><<<dim3(8,64),256,0,stream>>>(xin_bf,DDIM,w_enc,DDIM,(void*)xs,HN,nullptr,0,DDIM);
    k_gemm<2,false><<<dim3(8,64),256,0,stream>>>(xin_bf,DDIM,w_gate,DDIM,(void*)gate,HN,nullptr,0,DDIM);
    k_rope<<<TLEN*4096/256,256,0,stream>>>(xs,cosT,sinT,q);
    k_phase_a<<<dim3(32,NCH),256,0,stream>>>(q,gate,/*qg=*/q,kgT,gle);   // gate dead after this
    k_vbt<<<NCH,256,0,stream>>>(xin_bf,vbT);
    k_qk<<<dim3(NCH,NH_),256,0,stream>>>(/*qg=*/q,kgT,Aall);
    k_out_intra<<<dim3(NCH,NH_,4),256,0,stream>>>(Aall,vbT,o);
    for(int half=0; half<2; half++){
      k_state<<<dim3(16,4,NH_),256,0,stream>>>(kgT,vbT,gle,ST,half);
      k_out_inter<<<dim3(15,NH_,4),256,0,stream>>>(/*qg=*/q,ST,o,half);
    }
    k_ln<<<dim3(TLEN,NH_),256,0,stream>>>(o,oln);
    for(int h=0;h<4;h++)
      k_gemm<3,false><<<dim3(8,16),256,0,stream>>>(
        oln + (size_t)h*TLEN*DDIM, DDIM, w_encv + (size_t)h*NDIM*DDIM, DDIM,
        (void*)(q + h*NDIM), HN, xs + h*NDIM, HN, DDIM);
    k_gemm<0,true><<<dim3(8,2,8),256,0,stream>>>(q,HN,w_dec,HN,(void*)yraw,DDIM,nullptr,0,1024);
    k_post<<<TLEN,256,0,stream>>>(yraw,xin,x);
  }
  k_final<<<TLEN,256,0,stream>>>(x,x0,backout,xf);
  k_cvt<<<4096,256,0,stream>>>(lm_w, w_lm, VP_*DDIM);
  k_gemm<0,false><<<dim3(8,393),256,0,stream>>>(xf,DDIM,w_lm,DDIM,(void*)out,VP_,nullptr,0,DDIM);
}

// Round 5
// 976.459 us; speedup vs baseline: 1.9687x; 1.2796x over previous
//
#include <hip/hip_runtime.h>
#include <math.h>

#define TLEN 1024
#define DDIM 256
#define NH_  4
#define NDIM 2048
#define HN   8192
#define NCH  16
#define CHK  64
#define VP_  50304
#define SCALE_Q 0.022097086912079608f  // 2048^-0.5

typedef unsigned short u16;
typedef __attribute__((ext_vector_type(8))) short short8;
typedef __attribute__((ext_vector_type(4))) float f32x4;

#define MFMA16(a,b,c) __builtin_amdgcn_mfma_f32_16x16x32_bf16((a),(b),(c),0,0,0)

__device__ __forceinline__ float bf2f(u16 u){ return __uint_as_float(((unsigned)u)<<16); }
__device__ __forceinline__ u16 f2bf(float f){
  unsigned x = __float_as_uint(f);
  return (u16)((x + 0x7fffu + ((x>>16)&1u)) >> 16);
}
__device__ __forceinline__ float wave_sum(float v){
  #pragma unroll
  for(int o=1;o<64;o<<=1) v += __shfl_xor(v,o,64);
  return v;
}
__device__ __forceinline__ float block_sum(float v, float* tmp){
  v = wave_sum(v);
  __syncthreads();
  if((threadIdx.x&63)==0) tmp[threadIdx.x>>6]=v;
  __syncthreads();
  return tmp[0]+tmp[1]+tmp[2]+tmp[3];
}

// ---- LDS tile helpers: 64-col bf16 tiles, rows 128B, XOR-swizzled 16B slots ----
__device__ __forceinline__ void ld_tile(u16* dst, const u16* src, int ldg, int tid){
  #pragma unroll
  for(int p=0;p<2;p++){
    int r = p*32 + (tid>>3), cb = tid&7;
    short8 v = *(const short8*)(src + (size_t)r*ldg + cb*8);
    *(short8*)((char*)dst + r*128 + ((cb*16) ^ ((r&7)<<4))) = v;
  }
}
__device__ __forceinline__ short8 frag64(const u16* lds, int row, int k){
  return *(const short8*)((const char*)lds + row*128 + ((k*2) ^ ((row&7)<<4)));
}

// ---- setup kernels ----
__global__ void k_tables(float* cosT, float* sinT){
  int t = blockIdx.x, i = threadIdx.x; // 128 threads
  float inv_freq = exp2f(-18.0f * (float)(2*i) * (1.0f/256.0f));
  float fr = (float)t * inv_freq;
  float xsc = ((float)(2*i) + 102.4f) * (1.0f/358.4f);
  float power = ((float)t - 512.0f) * (1.0f/512.0f);
  float sc = exp2f(power * log2f(xsc));
  cosT[t*128+i] = cosf(fr)*sc;
  sinT[t*128+i] = sinf(fr)*sc;
}
__global__ void k_cvt(const float* in, u16* out, int n){
  for(int i = blockIdx.x*blockDim.x + threadIdx.x; i < n; i += gridDim.x*blockDim.x)
    out[i] = f2bf(in[i]);
}
__global__ __launch_bounds__(256) void k_embed(const float* emb, const int* idx, float* x, float* x0){
  __shared__ float tmp[4];
  int t = blockIdx.x, d = threadIdx.x;
  float v = emb[(size_t)idx[t]*DDIM + d];
  float s = block_sum(v*v, tmp);
  float o = v * rsqrtf(s*(1.0f/DDIM) + 1e-5f);
  x[t*DDIM+d]=o; x0[t*DDIM+d]=o;
}
__global__ void k_xin(const float* x, const float* x0, const float* rl, const float* xl, int li,
                      float* xin, u16* xin_bf, float* yraw){
  int i = blockIdx.x*256 + threadIdx.x;
  float v = rl[li]*x[i] + xl[li]*x0[i];
  xin[i]=v; xin_bf[i]=f2bf(v); yraw[i]=0.f;
}

// ---- generic bf16 GEMM: C = epi(A(MxK) @ B(NxK)^T) ----
// EPI: 0=fp32 store(/atomic), 1=sqrelu->bf16, 2=sqrelu/1024->bf16
template<int EPI, bool ATOMIC>
__global__ __launch_bounds__(256) void k_gemm(
  const u16* __restrict__ A, int lda, const u16* __restrict__ B, int ldb,
  void* Cv, int ldc, int kchunk)
{
  __shared__ __align__(16) u16 sA[128*64];
  __shared__ __align__(16) u16 sB[128*64];
  const int m0 = blockIdx.x*128, n0 = blockIdx.y*128;
  const int k0 = blockIdx.z*kchunk;
  const int tid = threadIdx.x, lane = tid&63, wv = tid>>6;
  const int wr = (wv>>1)*64, wc = (wv&1)*64;
  f32x4 acc[4][4];
  #pragma unroll
  for(int i=0;i<4;i++)
    #pragma unroll
    for(int j=0;j<4;j++) acc[i][j] = (f32x4){0.f,0.f,0.f,0.f};
  for(int kb=0; kb<kchunk; kb+=64){
    __syncthreads();
    #pragma unroll
    for(int p=0;p<4;p++){
      int r = p*32 + (tid>>3), cb = tid&7;
      short8 va = *(const short8*)(A + (size_t)(m0+r)*lda + k0+kb + cb*8);
      short8 vb = *(const short8*)(B + (size_t)(n0+r)*ldb + k0+kb + cb*8);
      int off = r*128 + ((cb*16) ^ ((r&7)<<4));
      *(short8*)((char*)sA + off) = va;
      *(short8*)((char*)sB + off) = vb;
    }
    __syncthreads();
    #pragma unroll
    for(int ks=0;ks<2;ks++){
      short8 af[4], bfr[4];
      int kk = ks*32 + 8*(lane>>4);
      #pragma unroll
      for(int i=0;i<4;i++){
        af[i]  = frag64(sA, wr + i*16 + (lane&15), kk);
        bfr[i] = frag64(sB, wc + i*16 + (lane&15), kk);
      }
      #pragma unroll
      for(int i=0;i<4;i++)
        #pragma unroll
        for(int j=0;j<4;j++)
          acc[i][j] = MFMA16(af[i], bfr[j], acc[i][j]);
    }
  }
  const int rb = 4*(lane>>4), cb2 = lane&15;
  #pragma unroll
  for(int i=0;i<4;i++)
    #pragma unroll
    for(int j=0;j<4;j++){
      int col = n0 + wc + j*16 + cb2;
      #pragma unroll
      for(int r=0;r<4;r++){
        int row = m0 + wr + i*16 + rb + r;
        float v = acc[i][j][r];
        if(EPI==0){
          float* C = (float*)Cv;
          if(ATOMIC) atomicAdd(C + (size_t)row*ldc + col, v);
          else C[(size_t)row*ldc + col] = v;
        } else {
          float a = v>0.f ? v*v : 0.f;
          if(EPI==2) a *= (1.0f/1024.0f);
          ((u16*)Cv)[(size_t)row*ldc + col] = f2bf(a);
        }
      }
    }
}

// ---- ys GEMM, batched over heads on blockIdx.z: xy = xs * sqrelu(oln @ encv^T) ----
__global__ __launch_bounds__(256) void k_gemm_ys(
  const u16* __restrict__ olnp, const u16* __restrict__ wvp,
  const u16* __restrict__ xs, u16* __restrict__ xy)
{
  __shared__ __align__(16) u16 sA[128*64];
  __shared__ __align__(16) u16 sB[128*64];
  const int m0 = blockIdx.x*128, n0 = blockIdx.y*128, h = blockIdx.z;
  const u16* A = olnp + (size_t)h*TLEN*DDIM;
  const u16* B = wvp  + (size_t)h*NDIM*DDIM;
  const int tid = threadIdx.x, lane = tid&63, wv = tid>>6;
  const int wr = (wv>>1)*64, wc = (wv&1)*64;
  f32x4 acc[4][4];
  #pragma unroll
  for(int i=0;i<4;i++)
    #pragma unroll
    for(int j=0;j<4;j++) acc[i][j] = (f32x4){0.f,0.f,0.f,0.f};
  for(int kb=0; kb<DDIM; kb+=64){
    __syncthreads();
    #pragma unroll
    for(int p=0;p<4;p++){
      int r = p*32 + (tid>>3), cb = tid&7;
      short8 va = *(const short8*)(A + (size_t)(m0+r)*DDIM + kb + cb*8);
      short8 vb = *(const short8*)(B + (size_t)(n0+r)*DDIM + kb + cb*8);
      int off = r*128 + ((cb*16) ^ ((r&7)<<4));
      *(short8*)((char*)sA + off) = va;
      *(short8*)((char*)sB + off) = vb;
    }
    __syncthreads();
    #pragma unroll
    for(int ks=0;ks<2;ks++){
      short8 af[4], bfr[4];
      int kk = ks*32 + 8*(lane>>4);
      #pragma unroll
      for(int i=0;i<4;i++){
        af[i]  = frag64(sA, wr + i*16 + (lane&15), kk);
        bfr[i] = frag64(sB, wc + i*16 + (lane&15), kk);
      }
      #pragma unroll
      for(int i=0;i<4;i++)
        #pragma unroll
        for(int j=0;j<4;j++)
          acc[i][j] = MFMA16(af[i], bfr[j], acc[i][j]);
    }
  }
  const int rb = 4*(lane>>4), cb2 = lane&15;
  #pragma unroll
  for(int i=0;i<4;i++)
    #pragma unroll
    for(int j=0;j<4;j++){
      int col = h*NDIM + n0 + wc + j*16 + cb2;
      #pragma unroll
      for(int r=0;r<4;r++){
        int row = m0 + wr + i*16 + rb + r;
        float v = acc[i][j][r];
        float a = v>0.f ? v*v : 0.f;
        a *= bf2f(xs[(size_t)row*HN + col]);
        xy[(size_t)row*HN + col] = f2bf(a);
      }
    }
}

// ---- phase A (rope fused): gate cumsum -> qg, kg (in-place over gate), kgT, gle ----
__global__ void k_phase_a(const u16* __restrict__ xs, u16* __restrict__ gate,
                          const float* __restrict__ cosT, const float* __restrict__ sinT,
                          u16* __restrict__ qg, u16* __restrict__ kgT, float* __restrict__ gle){
  int c = blockIdx.y;
  int j = blockIdx.x*256 + threadIdx.x;
  int h = j>>11, n = j&2047;
  int cc = j & 255;          // position within rope group of 256
  int ci = cc & 127;         // cos/sin column
  bool hi_ = cc >= 128;
  int poff = hi_ ? -128 : 128;
  size_t base = (size_t)c*CHK*HN + j;
  float gsum = 0.f;
  #pragma unroll
  for(int t=0;t<CHK;t++) gsum -= bf2f(gate[base + (size_t)t*HN]);
  float egsum = expf(gsum);
  u16 kv[64];
  float gc = 0.f;
  #pragma unroll
  for(int t=0;t<CHK;t++){
    size_t ix = base + (size_t)t*HN;
    gc -= bf2f(gate[ix]);
    int tt = c*CHK + t;
    float own = bf2f(xs[ix]), oth = bf2f(xs[ix + poff]);
    float cs = cosT[tt*128+ci], sn = sinT[tt*128+ci];
    float qv = hi_ ? (own*cs + oth*sn) : (own*cs - oth*sn);
    float e1 = expf(gc);
    qg[ix] = f2bf(qv * e1 * SCALE_Q);
    u16 kgv = f2bf(qv / e1);
    gate[ix] = kgv;            // kg in-place (each elem read before overwritten)
    kv[t] = kgv;
  }
  u16* kb = kgT + (((size_t)c*NH_ + h)*NDIM + n)*CHK;
  #pragma unroll
  for(int p=0;p<8;p++){
    short8 v;
    #pragma unroll
    for(int e=0;e<8;e++) v[e] = (short)kv[p*8+e];
    *(short8*)(kb + p*8) = v;
  }
  gle[(size_t)c*HN + j] = egsum;
}

// ---- vbT[c][d][t] = xin_bf[c*64+t][d] ----
__global__ __launch_bounds__(256) void k_vbt(const u16* __restrict__ xin_bf, u16* __restrict__ vbT){
  int c = blockIdx.x, tid = threadIdx.x;
  __shared__ u16 s[64*DDIM];
  #pragma unroll
  for(int p=0;p<8;p++){
    int idx = p*256+tid; int t = idx>>5, cb = idx&31;
    *(short8*)(s + t*DDIM + cb*8) = *(const short8*)(xin_bf + ((size_t)c*CHK + t)*DDIM + cb*8);
  }
  __syncthreads();
  int d = tid;
  u16 col[64];
  #pragma unroll
  for(int t=0;t<64;t++) col[t] = s[t*DDIM + d];
  u16* dst = vbT + ((size_t)c*DDIM + d)*CHK;
  #pragma unroll
  for(int p=0;p<8;p++){
    short8 v;
    #pragma unroll
    for(int e=0;e<8;e++) v[e] = (short)col[p*8+e];
    *(short8*)(dst + p*8) = v;
  }
}

// ---- A partials: Apart[kz][c][h][t][s] = qg[:,kz*512:+512] @ kg^T slice ----
__global__ __launch_bounds__(256) void k_qk_part(const u16* __restrict__ qg, const u16* __restrict__ kg,
                                                 float* __restrict__ Apart){
  int c = blockIdx.x, h = blockIdx.y, kz = blockIdx.z;
  int tid = threadIdx.x, lane = tid&63, wv = tid>>6;
  __shared__ __align__(16) u16 sQ[2][64*64], sK[2][64*64];
  const u16* qb = qg + (size_t)c*CHK*HN + h*NDIM + kz*512;
  const u16* kb = kg + (size_t)c*CHK*HN + h*NDIM + kz*512;
  f32x4 acc[4];
  #pragma unroll
  for(int j=0;j<4;j++) acc[j] = (f32x4){0.f,0.f,0.f,0.f};
  ld_tile(sQ[0], qb, HN, tid);
  ld_tile(sK[0], kb, HN, tid);
  __syncthreads();
  for(int kt=0; kt<8; kt++){
    if(kt<7){
      ld_tile(sQ[(kt+1)&1], qb + (kt+1)*64, HN, tid);
      ld_tile(sK[(kt+1)&1], kb + (kt+1)*64, HN, tid);
    }
    #pragma unroll
    for(int kh=0;kh<2;kh++){
      int kk = kh*32 + 8*(lane>>4);
      short8 af = frag64(sQ[kt&1], wv*16 + (lane&15), kk);
      #pragma unroll
      for(int j=0;j<4;j++){
        short8 b = frag64(sK[kt&1], j*16 + (lane&15), kk);
        acc[j] = MFMA16(af, b, acc[j]);
      }
    }
    __syncthreads();
  }
  int rb = 4*(lane>>4), cl = lane&15;
  float* ab = Apart + (size_t)kz*(NCH*NH_*4096) + ((size_t)c*NH_+h)*4096;
  #pragma unroll
  for(int j=0;j<4;j++)
    #pragma unroll
    for(int r=0;r<4;r++){
      int t = wv*16 + rb + r, s = j*16 + cl;
      ab[t*64 + s] = acc[j][r];
    }
}

// ---- reduce partials + causal mask -> Aall bf16 ----
__global__ __launch_bounds__(256) void k_amask(const float* __restrict__ Apart, u16* __restrict__ Aall){
  int c = blockIdx.x, h = blockIdx.y, tid = threadIdx.x;
  size_t base = ((size_t)c*NH_ + h)*4096;
  #pragma unroll
  for(int e=0;e<16;e++){
    int idx = e*256 + tid;
    int t = idx>>6, s = idx&63;
    float sum = 0.f;
    #pragma unroll
    for(int kz=0;kz<4;kz++)
      sum += Apart[(size_t)kz*(NCH*NH_*4096) + base + idx];
    Aall[base + idx] = f2bf((s<=t)? sum : 0.f);
  }
}

// ---- pass 1: boundary states ST[c][h][d][n], c=0..14 (full n, single launch) ----
__global__ __launch_bounds__(256) void k_state(const u16* __restrict__ kgT, const u16* __restrict__ vbT,
                                               const float* __restrict__ gle, u16* __restrict__ ST){
  int nb = blockIdx.x, db = blockIdx.y, h = blockIdx.z;   // nb 0..31
  int tid = threadIdx.x, lane = tid&63, wv = tid>>6;
  __shared__ __align__(16) u16 sK[64*64], sV[64*64], sD[64*64];
  int ng = nb*64;
  f32x4 S[4];
  #pragma unroll
  for(int fn=0;fn<4;fn++) S[fn] = (f32x4){0.f,0.f,0.f,0.f};
  for(int c=0;c<15;c++){
    __syncthreads();
    ld_tile(sK, kgT + (((size_t)c*NH_ + h)*NDIM + ng)*CHK, CHK, tid);   // rows n, cols t
    ld_tile(sV, vbT + ((size_t)c*DDIM + db*64)*CHK, CHK, tid);          // rows d, cols t
    __syncthreads();
    // S += U, then S *= e^{g_last}[n]   (kS = kg*e^{g_last})
    #pragma unroll
    for(int kh=0;kh<2;kh++){
      int kk = kh*32 + 8*(lane>>4);
      short8 af = frag64(sV, wv*16 + (lane&15), kk);
      #pragma unroll
      for(int fn=0;fn<4;fn++){
        short8 b = frag64(sK, fn*16 + (lane&15), kk);
        S[fn] = MFMA16(af, b, S[fn]);
      }
    }
    #pragma unroll
    for(int fn=0;fn<4;fn++){
      float gv = gle[(size_t)c*HN + h*NDIM + ng + fn*16 + (lane&15)];
      S[fn][0]*=gv; S[fn][1]*=gv; S[fn][2]*=gv; S[fn][3]*=gv;
    }
    __syncthreads();
    #pragma unroll
    for(int fn=0;fn<4;fn++)
      #pragma unroll
      for(int r=0;r<4;r++){
        int d = wv*16 + 4*(lane>>4) + r, n = fn*16 + (lane&15);
        *(u16*)((char*)sD + d*128 + ((n*2)^((d&7)<<4))) = f2bf(S[fn][r]);
      }
    __syncthreads();
    #pragma unroll
    for(int p=0;p<2;p++){
      int ii = p*256 + tid;
      int dl = ii>>3, seg = ii&7;
      short8 v = frag64(sD, dl, seg*8);
      *(short8*)(ST + (((size_t)c*NH_ + h)*DDIM + db*64 + dl)*NDIM + ng + seg*8) = v;
    }
  }
}

// ---- pass 2a: o[h][t][d] = Amask @ vb  (init store) ----
__global__ __launch_bounds__(256) void k_out_intra(const u16* __restrict__ Aall, const u16* __restrict__ vbT,
                                                   float* __restrict__ o){
  int c = blockIdx.x, h = blockIdx.y, db = blockIdx.z;
  int tid = threadIdx.x, lane = tid&63, wv = tid>>6;
  __shared__ __align__(16) u16 sA[64*64], sV[64*64];
  ld_tile(sA, Aall + ((size_t)c*NH_ + h)*CHK*CHK, CHK, tid);
  ld_tile(sV, vbT + ((size_t)c*DDIM + db*64)*CHK, CHK, tid);
  f32x4 acc[4];
  #pragma unroll
  for(int j=0;j<4;j++) acc[j] = (f32x4){0.f,0.f,0.f,0.f};
  __syncthreads();
  #pragma unroll
  for(int kh=0;kh<2;kh++){
    int kk = kh*32 + 8*(lane>>4);
    short8 af = frag64(sA, wv*16 + (lane&15), kk);
    #pragma unroll
    for(int j=0;j<4;j++){
      short8 b = frag64(sV, j*16 + (lane&15), kk);
      acc[j] = MFMA16(af, b, acc[j]);
    }
  }
  int rb = 4*(lane>>4), cl = lane&15;
  #pragma unroll
  for(int j=0;j<4;j++){
    int d = db*64 + j*16 + cl;
    #pragma unroll
    for(int r=0;r<4;r++){
      int t = c*CHK + wv*16 + rb + r;
      o[((size_t)h*TLEN + t)*DDIM + d] = acc[j][r];
    }
  }
}

// ---- pass 2b: o[h][t][d] += qg @ ST_{c-1}  (full n, single launch) ----
__global__ __launch_bounds__(256) void k_out_inter(const u16* __restrict__ qg, const u16* __restrict__ ST,
                                                   float* __restrict__ o){
  int c = blockIdx.x + 1, h = blockIdx.y, db = blockIdx.z;
  int tid = threadIdx.x, lane = tid&63, wv = tid>>6;
  __shared__ __align__(16) u16 sQ[2][64*64];
  f32x4 acc[4];
  #pragma unroll
  for(int j=0;j<4;j++) acc[j] = (f32x4){0.f,0.f,0.f,0.f};
  const u16* stb = ST + (((size_t)(c-1)*NH_ + h)*DDIM + db*64)*NDIM;
  const u16* qb  = qg + (size_t)c*CHK*HN + h*NDIM;
  ld_tile(sQ[0], qb, HN, tid);
  short8 bn[8];
  #pragma unroll
  for(int u=0;u<8;u++)
    bn[u] = *(const short8*)(stb + (size_t)((u&3)*16 + (lane&15))*NDIM + (u>>2)*32 + 8*(lane>>4));
  __syncthreads();
  for(int kt=0; kt<32; kt++){
    short8 bc[8];
    #pragma unroll
    for(int u=0;u<8;u++) bc[u] = bn[u];
    if(kt<31){
      #pragma unroll
      for(int u=0;u<8;u++)
        bn[u] = *(const short8*)(stb + (size_t)((u&3)*16 + (lane&15))*NDIM + (kt+1)*64 + (u>>2)*32 + 8*(lane>>4));
      ld_tile(sQ[(kt+1)&1], qb + (kt+1)*64, HN, tid);
    }
    #pragma unroll
    for(int kh=0;kh<2;kh++){
      int kk = kh*32 + 8*(lane>>4);
      short8 af = frag64(sQ[kt&1], wv*16 + (lane&15), kk);
      #pragma unroll
      for(int j=0;j<4;j++) acc[j] = MFMA16(af, bc[kh*4+j], acc[j]);
    }
    __syncthreads();
  }
  int rb = 4*(lane>>4), cl = lane&15;
  #pragma unroll
  for(int j=0;j<4;j++){
    int d = db*64 + j*16 + cl;
    #pragma unroll
    for(int r=0;r<4;r++){
      int t = c*CHK + wv*16 + rb + r;
      size_t ix = ((size_t)h*TLEN + t)*DDIM + d;
      o[ix] += acc[j][r];
    }
  }
}

// ---- layernorm over d of o[h][t][d] -> oln[h][t][d] bf16 ----
__global__ __launch_bounds__(256) void k_ln(const float* __restrict__ o, u16* __restrict__ oln){
  __shared__ float tmp[4];
  int t = blockIdx.x, h = blockIdx.y, d = threadIdx.x;
  size_t ix = ((size_t)h*TLEN + t)*DDIM + d;
  float v = o[ix];
  float s1 = block_sum(v, tmp);
  float m = s1*(1.0f/DDIM);
  float cv = v - m;
  float s2 = block_sum(cv*cv, tmp);
  oln[ix] = f2bf(cv * rsqrtf(s2*(1.0f/DDIM) + 1e-5f));
}

// ---- dec epilogue: layernorm(yraw) + xin, then rmsnorm -> x ----
__global__ __launch_bounds__(256) void k_post(const float* yraw, const float* xin, float* x){
  __shared__ float tmp[4];
  int t = blockIdx.x, d = threadIdx.x;
  float v = yraw[t*DDIM+d];
  float s1 = block_sum(v, tmp);
  float m = s1*(1.0f/DDIM);
  float cvt = v - m;
  float s2 = block_sum(cvt*cvt, tmp);
  float y = cvt * rsqrtf(s2*(1.0f/DDIM) + 1e-5f);
  float xn = y + xin[t*DDIM+d];
  float s3 = block_sum(xn*xn, tmp);
  x[t*DDIM+d] = xn * rsqrtf(s3*(1.0f/DDIM) + 1e-5f);
}

__global__ __launch_bounds__(256) void k_final(const float* x, const float* x0, const float* bl, u16* xf){
  __shared__ float tmp[4];
  int t = blockIdx.x, d = threadIdx.x;
  float v = x[t*DDIM+d] - bl[0]*x0[t*DDIM+d];
  float s = block_sum(v*v, tmp);
  xf[t*DDIM+d] = f2bf(v * rsqrtf(s*(1.0f/DDIM) + 1e-5f));
}

extern "C" void kernel_launch(void* const* d_in, const int* in_sizes, int n_in,
                              void* d_out, int out_size, void* d_ws, size_t ws_size,
                              hipStream_t stream){
  (void)in_sizes; (void)n_in; (void)out_size; (void)ws_size;
  const float* embed_w = (const float*)d_in[0];
  const float* lm_w    = (const float*)d_in[1];
  const float* enc_w   = (const float*)d_in[2];
  const float* gate_w  = (const float*)d_in[3];
  const float* dec_w   = (const float*)d_in[4];
  const float* encv_w  = (const float*)d_in[5];
  const float* backout = (const float*)d_in[6];
  const float* rlam    = (const float*)d_in[7];
  const float* xlam    = (const float*)d_in[8];
  const int*   idx     = (const int*)d_in[9];
  float* out = (float*)d_out;

  // ---- workspace layout: ~112 MB (round-2's 117.7 MB passed) ----
  char* p = (char*)d_ws;
  auto alloc = [&](size_t b)->char*{ char* r=p; p += (b+255)&~(size_t)255; return r; };
  float* cosT = (float*)alloc((size_t)TLEN*128*4);
  float* sinT = (float*)alloc((size_t)TLEN*128*4);
  float* x    = (float*)alloc((size_t)TLEN*DDIM*4);
  float* x0   = (float*)alloc((size_t)TLEN*DDIM*4);
  float* xin  = (float*)alloc((size_t)TLEN*DDIM*4);
  u16* xin_bf = (u16*)alloc((size_t)TLEN*DDIM*2);
  u16* xs     = (u16*)alloc((size_t)TLEN*HN*2);        // 16 MB
  u16* q      = (u16*)alloc((size_t)TLEN*HN*2);        // 16 MB: qg, later xy
  u16* gate   = (u16*)alloc((size_t)TLEN*HN*2);        // 16 MB: gate -> kg (in-place)
  (void)alloc((size_t)15*NH_*DDIM*NDIM*2 - (size_t)TLEN*HN*2);  // ST extension (~14.7 MB)
  u16* ST     = gate;   // 31 MB region; live k_state..k_out_inter (kg dead by then)
  u16* w_lm   = gate;   // 25.8 MB; used after layer loop only
  u16* kgT    = (u16*)alloc((size_t)NCH*NH_*NDIM*CHK*2); // 16 MB
  float* gle  = (float*)alloc((size_t)NCH*HN*4);
  u16* vbT    = (u16*)alloc((size_t)NCH*DDIM*CHK*2);
  u16* Aall   = (u16*)alloc((size_t)NCH*NH_*CHK*CHK*2);
  float* Apart= (float*)alloc((size_t)4*NCH*NH_*CHK*CHK*4); // 4 MB
  float* o    = (float*)alloc((size_t)NH_*TLEN*DDIM*4);  // 4 MB
  u16* oln    = (u16*)alloc((size_t)NH_*TLEN*DDIM*2);
  float* yraw = (float*)alloc((size_t)TLEN*DDIM*4);
  u16* xf     = (u16*)alloc((size_t)TLEN*DDIM*2);
  u16* w_enc  = (u16*)alloc((size_t)HN*DDIM*2);
  u16* w_gate = (u16*)alloc((size_t)HN*DDIM*2);
  u16* w_dec  = (u16*)alloc((size_t)DDIM*HN*2);
  u16* w_encv = (u16*)alloc((size_t)NH_*NDIM*DDIM*2);

  k_tables<<<TLEN,128,0,stream>>>(cosT,sinT);
  k_cvt<<<2048,256,0,stream>>>(enc_w,  w_enc,  HN*DDIM);
  k_cvt<<<2048,256,0,stream>>>(gate_w, w_gate, HN*DDIM);
  k_cvt<<<2048,256,0,stream>>>(dec_w,  w_dec,  DDIM*HN);
  k_cvt<<<2048,256,0,stream>>>(encv_w, w_encv, NH_*NDIM*DDIM);
  k_embed<<<TLEN,256,0,stream>>>(embed_w, idx, x, x0);

  for(int li=0; li<4; li++){
    k_xin<<<TLEN,256,0,stream>>>(x,x0,rlam,xlam,li,xin,xin_bf,yraw);
    k_gemm<1,false><<<dim3(8,64),256,0,stream>>>(xin_bf,DDIM,w_enc,DDIM,(void*)xs,HN,DDIM);
    k_gemm<2,false><<<dim3(8,64),256,0,stream>>>(xin_bf,DDIM,w_gate,DDIM,(void*)gate,HN,DDIM);
    k_phase_a<<<dim3(32,NCH),256,0,stream>>>(xs,gate,cosT,sinT,/*qg=*/q,kgT,gle); // rope fused; kg in gate
    k_vbt<<<NCH,256,0,stream>>>(xin_bf,vbT);
    k_qk_part<<<dim3(NCH,NH_,4),256,0,stream>>>(/*qg=*/q,/*kg=*/gate,Apart);
    k_amask<<<dim3(NCH,NH_),256,0,stream>>>(Apart,Aall);
    k_out_intra<<<dim3(NCH,NH_,4),256,0,stream>>>(Aall,vbT,o);
    k_state<<<dim3(32,4,NH_),256,0,stream>>>(kgT,vbT,gle,ST);       // overwrites kg region (dead)
    k_out_inter<<<dim3(15,NH_,4),256,0,stream>>>(/*qg=*/q,ST,o);
    k_ln<<<dim3(TLEN,NH_),256,0,stream>>>(o,oln);
    k_gemm_ys<<<dim3(8,16,NH_),256,0,stream>>>(oln,w_encv,xs,/*xy=*/q);
    k_gemm<0,true><<<dim3(8,2,8),256,0,stream>>>(q,HN,w_dec,HN,(void*)yraw,DDIM,1024);
    k_post<<<TLEN,256,0,stream>>>(yraw,xin,x);
  }
  k_final<<<TLEN,256,0,stream>>>(x,x0,backout,xf);
  k_cvt<<<4096,256,0,stream>>>(lm_w, w_lm, VP_*DDIM);
  k_gemm<0,false><<<dim3(8,393),256,0,stream>>>(xf,DDIM,w_lm,DDIM,(void*)out,VP_,DDIM);
}